// Round 2
// baseline (207.117 us; speedup 1.0000x reference)
//
#include <hip/hip_runtime.h>
#include <math.h>

// Problem constants (B=64, S=8192, D=32), fp32 in/out.
#define B_ 64
#define S_ 8192
#define D_ 32

// ---------------- Kernel 1: per-batch Gram matrix G = x^T x ----------------
// Grid: B_*8 blocks (8 chunks of 1024 rows per batch), 512 threads (8 waves).
// Each lane owns a 4x4 block of the 32x32 G: i0=(l/8)*4, j0=(l%8)*4.
// Two float4 loads per row; the 8-way duplicated addresses across lanes
// coalesce to the full 128B row (coalescer merges same-address lanes).
#define K1_CH 8
#define K1_ROWS (S_ / K1_CH)   // 1024
#define K1_WAVES 8

__global__ __launch_bounds__(512) void gram_k(const float* __restrict__ x,
                                              float* __restrict__ gpart) {
    const int blk = blockIdx.x;            // 512 blocks
    const int b  = blk >> 3;
    const int ch = blk & 7;
    const int t  = threadIdx.x;
    const int w  = t >> 6;
    const int l  = t & 63;
    const int i0 = ((l >> 3) & 7) << 2;    // 0,4,...,28
    const int j0 = (l & 7) << 2;           // 0,4,...,28

    const float* xb = x + ((size_t)b * S_ + (size_t)ch * K1_ROWS) * D_;

    float acc[4][4] = {};
    #pragma unroll 4
    for (int r = w; r < K1_ROWS; r += K1_WAVES) {
        const float* row = xb + r * D_;
        const float4 xi = *(const float4*)(row + i0);
        const float4 xj = *(const float4*)(row + j0);
        const float xiv[4] = {xi.x, xi.y, xi.z, xi.w};
        const float xjv[4] = {xj.x, xj.y, xj.z, xj.w};
        #pragma unroll
        for (int a = 0; a < 4; ++a)
            #pragma unroll
            for (int c = 0; c < 4; ++c)
                acc[a][c] = fmaf(xiv[a], xjv[c], acc[a][c]);
    }

    // Cross-wave reduction in LDS (8 waves x 1024 floats = 32 KiB).
    __shared__ float red[K1_WAVES][1024];
    #pragma unroll
    for (int a = 0; a < 4; ++a)
        #pragma unroll
        for (int c = 0; c < 4; ++c)
            red[w][l * 16 + a * 4 + c] = acc[a][c];
    __syncthreads();

    // 512 threads reduce 1024 elements (2 each), write partial G for this chunk.
    for (int e = t; e < 1024; e += 512) {
        float s = 0.f;
        #pragma unroll
        for (int ww = 0; ww < K1_WAVES; ++ww) s += red[ww][e];
        const int ll = e >> 4, ee = e & 15;
        const int i = (((ll >> 3) & 7) << 2) + (ee >> 2);
        const int j = ((ll & 7) << 2) + (ee & 3);
        gpart[(size_t)blk * 1024 + i * 32 + j] = s;
    }
}

// ------------- Kernel 2: tiny per-batch scores/softmax and M ---------------
// Grid: B_ blocks, 1024 threads. t=(r=t>>5, c=t&31). All 32x32 work in LDS,
// padded to [32][33] for bank-conflict-free column access.
// scores = softmax over q (axis=1) of P = Wq^T (G Wk); M[d][q] = sum_k Wv[d][k]*scores[q][k].
__global__ __launch_bounds__(1024) void attn_small(const float* __restrict__ gpart,
                                                   const float* __restrict__ Wq,
                                                   const float* __restrict__ Wk,
                                                   const float* __restrict__ Wv,
                                                   float* __restrict__ M) {
    __shared__ float GL[32][33], WqL[32][33], WkL[32][33], WvL[32][33];
    __shared__ float T1L[32][33], PL[32][33];
    __shared__ float mcol[32], scol[32];

    const int b = blockIdx.x;
    const int t = threadIdx.x;
    const int r = t >> 5, c = t & 31;

    float g = 0.f;
    #pragma unroll
    for (int cc = 0; cc < K1_CH; ++cc)
        g += gpart[(size_t)(b * K1_CH + cc) * 1024 + t];
    GL[r][c]  = g;
    WqL[r][c] = Wq[t];
    WkL[r][c] = Wk[t];
    WvL[r][c] = Wv[t];
    __syncthreads();

    // T1 = G @ Wk   (T1[d][k])
    float t1 = 0.f;
    #pragma unroll
    for (int e = 0; e < 32; ++e) t1 = fmaf(GL[r][e], WkL[e][c], t1);
    T1L[r][c] = t1;
    __syncthreads();

    // P[q][k] = sum_d Wq[d][q] * T1[d][k]   (r=q, c=k)
    float p = 0.f;
    #pragma unroll
    for (int d = 0; d < 32; ++d) p = fmaf(WqL[d][r], T1L[d][c], p);
    PL[r][c] = p;
    __syncthreads();

    // Column softmax over q for each k (stable).
    if (t < 32) {
        float m = -INFINITY;
        #pragma unroll
        for (int q = 0; q < 32; ++q) m = fmaxf(m, PL[q][t]);
        float s = 0.f;
        #pragma unroll
        for (int q = 0; q < 32; ++q) s += __expf(PL[q][t] - m);
        mcol[t] = m;
        scol[t] = 1.0f / s;
    }
    __syncthreads();
    // In-place: each thread rewrites only its own element.
    const float sc = __expf(PL[r][c] - mcol[c]) * scol[c];   // scores[q][k]
    PL[r][c] = sc;
    __syncthreads();

    // M[d][q] = sum_k Wv[d][k] * scores[q][k]   (r=d, c=q)
    float mm = 0.f;
    #pragma unroll
    for (int k = 0; k < 32; ++k) mm = fmaf(WvL[r][k], PL[c][k], mm);
    M[(size_t)b * 1024 + t] = mm;    // M[b][d][q], t = d*32+q
}

// ---------------- Kernel 3: out[b][q][s] = sum_d x[b][s][d] * M[b][d][q] ----
// Grid: B_*16 blocks, 256 threads; each thread computes 2 consecutive s.
// M reads are wave-uniform -> compiler scalarizes to s_load, FMAs take SGPR src.
// Stores: float2 along s, coalesced per q.
__global__ __launch_bounds__(256) void out_k(const float* __restrict__ x,
                                             const float* __restrict__ M,
                                             float* __restrict__ out) {
    const int blk = blockIdx.x;      // 1024 blocks
    const int b  = blk >> 4;
    const int sb = blk & 15;
    const int t  = threadIdx.x;
    const int s  = sb * 512 + t * 2;

    const float* Mb = M + (size_t)b * 1024;
    const float* xr = x + ((size_t)b * S_ + s) * D_;

    float4 xa[8], xc[8];
    #pragma unroll
    for (int i = 0; i < 8; ++i) {
        xa[i] = ((const float4*)xr)[i];        // row s
        xc[i] = ((const float4*)(xr + D_))[i]; // row s+1
    }

    float acc0[32] = {}, acc1[32] = {};
    #pragma unroll
    for (int d = 0; d < 32; ++d) {
        const float x0 = ((const float*)xa)[d];
        const float x1 = ((const float*)xc)[d];
        #pragma unroll
        for (int q = 0; q < 32; ++q) {
            const float m = Mb[d * 32 + q];
            acc0[q] = fmaf(m, x0, acc0[q]);
            acc1[q] = fmaf(m, x1, acc1[q]);
        }
    }

    float* ob = out + (size_t)b * D_ * S_ + s;
    #pragma unroll
    for (int q = 0; q < 32; ++q) {
        float2 v = make_float2(acc0[q], acc1[q]);
        *(float2*)(ob + (size_t)q * S_) = v;
    }
}

extern "C" void kernel_launch(void* const* d_in, const int* in_sizes, int n_in,
                              void* d_out, int out_size, void* d_ws, size_t ws_size,
                              hipStream_t stream) {
    const float* x  = (const float*)d_in[0];
    const float* Wq = (const float*)d_in[1];
    const float* Wk = (const float*)d_in[2];
    const float* Wv = (const float*)d_in[3];
    float* out = (float*)d_out;

    // ws layout: gpart[512][1024] (2 MiB) then M[64][1024] (256 KiB).
    float* gpart = (float*)d_ws;
    float* M     = gpart + (size_t)B_ * K1_CH * 1024;

    gram_k<<<B_ * K1_CH, 512, 0, stream>>>(x, gpart);
    attn_small<<<B_, 1024, 0, stream>>>(gpart, Wq, Wk, Wv, M);
    out_k<<<B_ * 16, 256, 0, stream>>>(x, M, out);
}

// Round 3
// 156.345 us; speedup vs baseline: 1.3247x; 1.3247x over previous
//
#include <hip/hip_runtime.h>
#include <math.h>

// Problem constants (B=64, S=8192, D=32), fp32 in/out.
#define B_ 64
#define S_ 8192
#define D_ 32

__device__ __forceinline__ void load_lds16(const float* g, float* l) {
    __builtin_amdgcn_global_load_lds(
        (const __attribute__((address_space(1))) void*)g,
        (__attribute__((address_space(3))) void*)l,
        16, 0, 0);
}

// ---------------- Kernel 1: per-batch Gram matrix G = x^T x ----------------
// 512 blocks (b, ch8): each handles 1024 rows as 4 sub-tiles of 256 rows.
// Stage 32KB linearly via global_load_lds (coalesced); compute reads are
// 8-distinct-address broadcasts (conflict-free, no swizzle needed).
// Lane owns a 4x4 block of G: i0=((l>>3)&7)*4, j0=(l&7)*4.
#define GR_SUB 256

__global__ __launch_bounds__(256) void gram_k(const float* __restrict__ x,
                                              float* __restrict__ gpart) {
    __shared__ float tile[GR_SUB * D_];    // 32 KB, linear layout
    const int blk = blockIdx.x;            // 512
    const int b   = blk >> 3;
    const int ch8 = blk & 7;
    const int t   = threadIdx.x;
    const int w   = t >> 6;
    const int l   = t & 63;
    const int i0  = ((l >> 3) & 7) << 2;
    const int j0  = (l & 7) << 2;

    const float* xb = x + ((size_t)b * S_ + (size_t)ch8 * 1024) * D_;

    float acc[4][4] = {};
    for (int sub = 0; sub < 4; ++sub) {
        const float* src = xb + (size_t)sub * GR_SUB * D_;
        #pragma unroll
        for (int k = 0; k < 8; ++k) {
            const int g = k * 256 + t;     // 16B granule index
            load_lds16(src + g * 4, tile + g * 4);
        }
        __syncthreads();                   // compiler drains vmcnt before barrier

        const int rbase = w * 64;
        #pragma unroll 4
        for (int rr = 0; rr < 64; ++rr) {
            const int r = rbase + rr;
            const float4 xi = *(const float4*)(tile + r * D_ + i0);
            const float4 xj = *(const float4*)(tile + r * D_ + j0);
            const float xiv[4] = {xi.x, xi.y, xi.z, xi.w};
            const float xjv[4] = {xj.x, xj.y, xj.z, xj.w};
            #pragma unroll
            for (int a = 0; a < 4; ++a)
                #pragma unroll
                for (int c = 0; c < 4; ++c)
                    acc[a][c] = fmaf(xiv[a], xjv[c], acc[a][c]);
        }
        __syncthreads();                   // before overwriting tile
    }

    // Cross-wave reduce: reuse tile as red[4][1024] (16 KB).
    float* red = tile;
    #pragma unroll
    for (int a = 0; a < 4; ++a)
        #pragma unroll
        for (int c = 0; c < 4; ++c)
            red[w * 1024 + l * 16 + a * 4 + c] = acc[a][c];
    __syncthreads();

    #pragma unroll
    for (int e = t; e < 1024; e += 256) {
        const float s = red[e] + red[1024 + e] + red[2048 + e] + red[3072 + e];
        const int ll = e >> 4, ee = e & 15;
        const int i = (((ll >> 3) & 7) << 2) + (ee >> 2);
        const int j = ((ll & 7) << 2) + (ee & 3);
        gpart[(size_t)blk * 1024 + i * 32 + j] = s;
    }
}

// ------------- Kernel 2: tiny per-batch scores/softmax and M ---------------
// (unchanged from the passing round-2 kernel)
#define K1_CH 8
__global__ __launch_bounds__(1024) void attn_small(const float* __restrict__ gpart,
                                                   const float* __restrict__ Wq,
                                                   const float* __restrict__ Wk,
                                                   const float* __restrict__ Wv,
                                                   float* __restrict__ M) {
    __shared__ float GL[32][33], WqL[32][33], WkL[32][33], WvL[32][33];
    __shared__ float T1L[32][33], PL[32][33];
    __shared__ float mcol[32], scol[32];

    const int b = blockIdx.x;
    const int t = threadIdx.x;
    const int r = t >> 5, c = t & 31;

    float g = 0.f;
    #pragma unroll
    for (int cc = 0; cc < K1_CH; ++cc)
        g += gpart[(size_t)(b * K1_CH + cc) * 1024 + t];
    GL[r][c]  = g;
    WqL[r][c] = Wq[t];
    WkL[r][c] = Wk[t];
    WvL[r][c] = Wv[t];
    __syncthreads();

    float t1 = 0.f;
    #pragma unroll
    for (int e = 0; e < 32; ++e) t1 = fmaf(GL[r][e], WkL[e][c], t1);
    T1L[r][c] = t1;
    __syncthreads();

    float p = 0.f;
    #pragma unroll
    for (int d = 0; d < 32; ++d) p = fmaf(WqL[d][r], T1L[d][c], p);
    PL[r][c] = p;
    __syncthreads();

    if (t < 32) {
        float m = -INFINITY;
        #pragma unroll
        for (int q = 0; q < 32; ++q) m = fmaxf(m, PL[q][t]);
        float s = 0.f;
        #pragma unroll
        for (int q = 0; q < 32; ++q) s += __expf(PL[q][t] - m);
        mcol[t] = m;
        scol[t] = 1.0f / s;
    }
    __syncthreads();
    const float sc = __expf(PL[r][c] - mcol[c]) * scol[c];
    PL[r][c] = sc;
    __syncthreads();

    float mm = 0.f;
    #pragma unroll
    for (int k = 0; k < 32; ++k) mm = fmaf(WvL[r][k], PL[c][k], mm);
    M[(size_t)b * 1024 + t] = mm;    // M[b][d][q]
}

// ---------------- Kernel 3: out[b][q][s] = sum_d x[b][s][d] * M[b][d][q] ----
// 2048 blocks x 256 thr, one 256-row tile each. Stage x tile via
// global_load_lds with inverse-XOR-swizzled SOURCE (16B granule j ^= r&7,
// involution) + same XOR on ds_read_b128 (T21 both-sides pattern) to break
// the 64-way same-bank conflict of a linear [256][32] row-wise read.
// Lane t owns row t: 8x float4 LDS reads, 1024 FMA (M via s_load, uniform),
// 32 lane-contiguous scalar stores.
#define OUT_ROWS 256

__global__ __launch_bounds__(256) void out_k(const float* __restrict__ x,
                                             const float* __restrict__ M,
                                             float* __restrict__ out) {
    __shared__ float tile[OUT_ROWS * D_];  // 32 KB
    const int blk = blockIdx.x;            // 2048
    const int b   = blk >> 5;
    const int ch  = blk & 31;
    const int t   = threadIdx.x;

    const float* src = x + ((size_t)b * S_ + (size_t)ch * OUT_ROWS) * D_;
    #pragma unroll
    for (int k = 0; k < 8; ++k) {
        const int g  = k * 256 + t;        // linear LDS granule
        const int r  = g >> 3, j = g & 7;
        const int gs = r * 8 + (j ^ (r & 7));  // pre-swizzled global granule
        load_lds16(src + gs * 4, tile + g * 4);
    }
    __syncthreads();

    const float* Mb = M + (size_t)b * 1024;
    float acc[32] = {};
    const int r = t;
    #pragma unroll
    for (int j = 0; j < 8; ++j) {
        const int pg = r * 8 + (j ^ (r & 7));
        const float4 xv = *(const float4*)(tile + pg * 4);
        const float xd[4] = {xv.x, xv.y, xv.z, xv.w};
        #pragma unroll
        for (int dd = 0; dd < 4; ++dd) {
            const int d = j * 4 + dd;
            #pragma unroll
            for (int q = 0; q < 32; ++q)
                acc[q] = fmaf(Mb[d * 32 + q], xd[dd], acc[q]);
        }
    }

    const int s = ch * OUT_ROWS + r;
    float* ob = out + (size_t)b * D_ * S_ + s;
    #pragma unroll
    for (int q = 0; q < 32; ++q)
        ob[(size_t)q * S_] = acc[q];
}

extern "C" void kernel_launch(void* const* d_in, const int* in_sizes, int n_in,
                              void* d_out, int out_size, void* d_ws, size_t ws_size,
                              hipStream_t stream) {
    const float* x  = (const float*)d_in[0];
    const float* Wq = (const float*)d_in[1];
    const float* Wk = (const float*)d_in[2];
    const float* Wv = (const float*)d_in[3];
    float* out = (float*)d_out;

    // ws layout: gpart[512][1024] (2 MiB) then M[64][1024] (256 KiB).
    float* gpart = (float*)d_ws;
    float* M     = gpart + (size_t)B_ * K1_CH * 1024;

    gram_k<<<B_ * K1_CH, 256, 0, stream>>>(x, gpart);
    attn_small<<<B_, 1024, 0, stream>>>(gpart, Wq, Wk, Wv, M);
    out_k<<<B_ * 32, 256, 0, stream>>>(x, M, out);
}